// Round 11
// baseline (141.908 us; speedup 1.0000x reference)
//
#include <hip/hip_runtime.h>

#define DEV __device__ __forceinline__

typedef unsigned short u16;
typedef unsigned int   u32;
typedef __attribute__((ext_vector_type(4)))  float f32x4;
typedef __attribute__((ext_vector_type(16))) float f32x16;
typedef __attribute__((ext_vector_type(8)))  short s16x8;
typedef __attribute__((ext_vector_type(2)))  u32   u32x2;

// Problem constants: B=2 S=2048 D=1024 H=16 DH=64. M = B*S = 4096.
// Workspace layout (bytes):
static constexpr size_t OFF_QBF  = 0;           // Q bf16 [4096][1024]   8388608
static constexpr size_t OFF_KBF  = 8388608;     // K bf16
static constexpr size_t OFF_VBF  = 16777216;    // V bf16
static constexpr size_t OFF_WCAT = 25165824;    // WqT|WkT|WvT bf16 [3072][1024]
static constexpr size_t OFF_WFT  = 31457280;    // WfT bf16 [1024][1024]
static constexpr size_t OFF_BIAS = 33554432;    // bq|bk|bv f32 [3072]
static constexpr size_t OFF_QKVH = 33566720;    // Qh|Kh|(unused) bf16 [4096][3072]
static constexpr size_t OFF_VT   = 58732544;    // Vt bf16 [1024 (h,e)][4096 (b,t)]
static constexpr size_t OFF_OBUF = 67121152;    // attn out bf16 [4096][1024]

// NOTE: v_cvt_pk_bf16_f32 inline asm is BANNED in this file (rounds 2/3/7
// all failed with it; rounds 1/4/5/8/9/10 passed without). All fp32->bf16
// goes through bit-level f2bf (RNE), verified since round 1.
DEV u16 f2bf(float f) {
  union { float f; u32 u; } a; a.f = f;
  u32 r = a.u + 0x7FFFu + ((a.u >> 16) & 1u);
  return (u16)(r >> 16);
}
DEV u32 f2bf2(float lo, float hi_) {    // pack two bf16 into u32 (lo in [15:0])
  return (u32)f2bf(lo) | ((u32)f2bf(hi_) << 16);
}

#if __has_builtin(__builtin_amdgcn_exp2f)
DEV float fast_exp2(float x) { return __builtin_amdgcn_exp2f(x); }
#else
DEV float fast_exp2(float x) { return exp2f(x); }
#endif

DEV f32x4 mfma16(s16x8 a, s16x8 b, f32x4 c) {
  return __builtin_amdgcn_mfma_f32_16x16x32_bf16(a, b, c, 0, 0, 0);
}
DEV f32x16 mfma32(s16x8 a, s16x8 b, f32x16 c) {
  return __builtin_amdgcn_mfma_f32_32x32x16_bf16(a, b, c, 0, 0, 0);
}

DEV void gload_lds16(const void* g, void* l) {   // 16B/lane direct global->LDS
  __builtin_amdgcn_global_load_lds(
      (__attribute__((address_space(1))) void*)g,
      (__attribute__((address_space(3))) void*)l, 16, 0, 0);
}

// ---------------- unified prep kernel (verified round 8) ----------------
__global__ __launch_bounds__(256) void prep_all_k(const float* __restrict__ Q,
                                                  const float* __restrict__ K,
                                                  const float* __restrict__ V,
                                                  const float* __restrict__ Wq,
                                                  const float* __restrict__ Wk,
                                                  const float* __restrict__ Wv,
                                                  const float* __restrict__ Wf,
                                                  const float* __restrict__ bq,
                                                  const float* __restrict__ bk,
                                                  const float* __restrict__ bv,
                                                  u16* __restrict__ QKVbf,
                                                  u16* __restrict__ Wcat,
                                                  u16* __restrict__ WfT,
                                                  float* __restrict__ biascat) {
  const int bid = blockIdx.x;
  __shared__ u16 t[64][72];
  if (bid < 12288) {
    size_t idx = (size_t)bid * 256 + threadIdx.x;   // < 3145728
    size_t tt  = idx >> 20;
    size_t r   = idx & 1048575;
    const float* src = (tt == 0) ? Q : (tt == 1) ? K : V;
    f32x4 v = *(const f32x4*)(src + r * 4);
    u32x2 o;
    o[0] = f2bf2(v[0], v[1]);
    o[1] = f2bf2(v[2], v[3]);
    *(u32x2*)(QKVbf + idx * 4) = o;
  } else if (bid < 13056) {
    const int q = bid - 12288;
    const int dt = q & 15, h = (q >> 4) & 15, z = q >> 8;
    const float* W = (z == 0) ? Wq : (z == 1) ? Wk : Wv;
#pragma unroll
    for (int p = 0; p < 16; ++p) {
      int idx = threadIdx.x + p * 256;
      int r = idx >> 6, e = idx & 63;
      t[r][e] = f2bf(W[((size_t)h * 1024 + dt * 64 + r) * 64 + e]);
    }
    __syncthreads();
#pragma unroll
    for (int p = 0; p < 16; ++p) {
      int idx = threadIdx.x + p * 256;
      int e = idx >> 6, r = idx & 63;
      Wcat[((size_t)z * 1024 + h * 64 + e) * 1024 + dt * 64 + r] = t[r][e];
    }
  } else if (bid < 13312) {
    const int q = bid - 13056;
    const int dt = q & 15, ft = q >> 4;
#pragma unroll
    for (int p = 0; p < 16; ++p) {
      int idx = threadIdx.x + p * 256;
      int r = idx >> 6, f = idx & 63;
      t[r][f] = f2bf(Wf[(size_t)(dt * 64 + r) * 1024 + ft * 64 + f]);
    }
    __syncthreads();
#pragma unroll
    for (int p = 0; p < 16; ++p) {
      int idx = threadIdx.x + p * 256;
      int f = idx >> 6, r = idx & 63;
      WfT[(size_t)(ft * 64 + f) * 1024 + dt * 64 + r] = t[r][f];
    }
  } else {
    int i = (bid - 13312) * 256 + threadIdx.x;
    if (i < 1024) biascat[i] = bq[i];
    else if (i < 2048) biascat[i] = bk[i - 1024];
    else if (i < 3072) biascat[i] = bv[i - 2048];
  }
}

// ---------------- GEMM core (m97 structure, verified rounds 1/8) ------------
// MODE 0: f32 out C[mm*ldc+nn]; MODE 1: bf16 out C[mm*ldc+nn];
// MODE 2: bf16 TRANSPOSED out C[nn*ldc+mm] (f2bf-packed 8B stores) -- for Vt.
template <int MODE>
DEV void gemm128(const u16* __restrict__ A, int lda,
                 const u16* __restrict__ B, int ldb,
                 const float* __restrict__ bias,
                 void* __restrict__ Cp, size_t ldc, int K) {
  __shared__ u16 Ash[128 * 32];
  __shared__ u16 Bsh[128 * 32];
  const int tid = threadIdx.x;
  const int lane = tid & 63;
  const int w = tid >> 6;
  const int wr = w >> 1, wc = w & 1;
  const int lr = lane >> 2;
  const int lc = (lane & 3) << 3;
  const int l15 = lane & 15, lg = lane >> 4;

  f32x4 acc[4][4];
#pragma unroll
  for (int i = 0; i < 4; ++i)
#pragma unroll
    for (int j = 0; j < 4; ++j) acc[i][j] = f32x4{0.f, 0.f, 0.f, 0.f};

  for (int kt = 0; kt < K; kt += 32) {
    if (kt) __syncthreads();
#pragma unroll
    for (int j = 0; j < 2; ++j) {
      const u16* ga = A + (size_t)(w * 32 + j * 16 + lr) * lda + kt + lc;
      gload_lds16(ga, (char*)Ash + (w * 2 + j) * 1024);
      const u16* gb = B + (size_t)(w * 32 + j * 16 + lr) * ldb + kt + lc;
      gload_lds16(gb, (char*)Bsh + (w * 2 + j) * 1024);
    }
    __syncthreads();
    s16x8 af[4], bv_[4];
#pragma unroll
    for (int i = 0; i < 4; ++i) {
      af[i]  = *(const s16x8*)&Ash[(wr * 64 + i * 16 + l15) * 32 + lg * 8];
      bv_[i] = *(const s16x8*)&Bsh[(wc * 64 + i * 16 + l15) * 32 + lg * 8];
    }
#pragma unroll
    for (int mf = 0; mf < 4; ++mf)
#pragma unroll
      for (int nf = 0; nf < 4; ++nf)
        acc[mf][nf] = mfma16(af[mf], bv_[nf], acc[mf][nf]);
  }
#pragma unroll
  for (int nf = 0; nf < 4; ++nf) {
    const int nn = wc * 64 + nf * 16 + l15;
    const float bvv = bias[nn];
#pragma unroll
    for (int mf = 0; mf < 4; ++mf) {
      if (MODE == 2) {
        const int mm0 = wr * 64 + mf * 16 + lg * 4;
        u32x2 d;
        d[0] = f2bf2(acc[mf][nf][0] + bvv, acc[mf][nf][1] + bvv);
        d[1] = f2bf2(acc[mf][nf][2] + bvv, acc[mf][nf][3] + bvv);
        *(u32x2*)((u16*)Cp + (size_t)nn * ldc + mm0) = d;
      } else {
#pragma unroll
        for (int j = 0; j < 4; ++j) {
          const int mm = wr * 64 + mf * 16 + lg * 4 + j;
          float v = acc[mf][nf][j] + bvv;
          if (MODE == 1) ((u16*)Cp)[(size_t)mm * ldc + nn] = f2bf(v);
          else           ((float*)Cp)[(size_t)mm * ldc + nn] = v;
        }
      }
    }
  }
}

__global__ __launch_bounds__(256) void proj_gemm_k(const u16* __restrict__ Qb,
                                                   const u16* __restrict__ Kb,
                                                   const u16* __restrict__ Vb,
                                                   const u16* __restrict__ Wcat,
                                                   const float* __restrict__ biascat,
                                                   u16* __restrict__ QKVh,
                                                   u16* __restrict__ Vt) {
  const int z = blockIdx.z;
  const u16* A = (z == 0) ? Qb : (z == 1) ? Kb : Vb;
  const int m0 = blockIdx.y * 128;
  const int nl = blockIdx.x * 128;
  if (z == 2) {
    gemm128<2>(A + (size_t)m0 * 1024, 1024,
               Wcat + (size_t)(2 * 1024 + nl) * 1024, 1024,
               biascat + 2 * 1024 + nl,
               Vt + (size_t)nl * 4096 + m0, 4096, 1024);
  } else {
    gemm128<1>(A + (size_t)m0 * 1024, 1024,
               Wcat + (size_t)(z * 1024 + nl) * 1024, 1024,
               biascat + z * 1024 + nl,
               QKVh + (size_t)m0 * 3072 + z * 1024 + nl, 3072, 1024);
  }
}

__global__ __launch_bounds__(256) void final_gemm_k(const u16* __restrict__ Obuf,
                                                    const u16* __restrict__ WfT,
                                                    const float* __restrict__ bf,
                                                    float* __restrict__ out) {
  const int m0 = blockIdx.y * 128;
  const int n0 = blockIdx.x * 128;
  gemm128<0>(Obuf + (size_t)m0 * 1024, 1024,
             WfT + (size_t)n0 * 1024, 1024,
             bf + n0,
             out + (size_t)m0 * 1024 + n0, 1024, 1024);
}

// ---------------- flash attention v10: 32x32 swapped-operand, LDS-lean ------
// Diagnosis (r10 PMC + accounting): LDS pipe ~100% busy; MfmaUtil pinned 27%.
// This version cuts LDS instructions per q-row ~2.3x:
//  - QK swapped:  sc = mfma32(A=K, B=Q)  -> D[t][s], s = lane&31. 8 K b128
//    reads now serve 32 q-rows/wave (was 16).
//  - P scatter: D-layout reg-quads are t-contiguous -> 8 x ds_write_b64
//    (f2bf2-packed) into plain P[s][t] rows (was 16 x ds_write_b16).
//  - PV swapped:  accO = mfma32(A=V^T, B=P) -> B-operand = P[s=l31][t contig]
//    = straight b128 row reads of what we just wrote (no transpose gather).
//  - row-sum l: in-lane (lane holds a full t-half for its s) + shfl_xor(32);
//    ones-MFMA removed.
// Layout provenance: C/D 32x32 formula col=lane&31,row=(reg&3)+8*(reg>>2)+
// 4*(lane>>5) [guide m74/m101, HW-verified]; A/B k-map k=(lane>>5)*8+i is the
// standard AMD pattern (analog of the 16x16x32 map verified here since r1).
// Staging + two-barrier schedule byte-identical to round 8. Fixed-max
// softmax kept. Deterministic: pure math, race-free barriers, epilogue
// barrier before K/V LDS reuse (round-3 lesson).
__global__ __launch_bounds__(256) void attn10_k(const u16* __restrict__ QKVh,
                                                const u16* __restrict__ Vt,
                                                u16* __restrict__ Obuf) {
  const int id = blockIdx.x;
  const int virt = (id & 7) * 64 + (id >> 3);   // XCD-aware bijection (512%8==0)
  const int qb = virt & 15;
  const int hb = virt >> 4;
  const int h = hb & 15, b = hb >> 4;

  const int tid = threadIdx.x, lane = tid & 63, w = tid >> 6;  // w in [0,4)
  const int l31 = lane & 31, hi = lane >> 5;
  const int swz = (l31 & 7) << 4;

  __shared__ u16 KVsh[2][64 * 64];  // [0]=K [t][e], [1]=V^T [e][t]; swizzled
  __shared__ u16 Psh[4][32 * 64];   // per-wave P [s][t], swizzled rows

  const size_t rowQ = (size_t)(b * 2048 + qb * 128);
  const u16* Qbase = QKVh + rowQ * 3072 + h * 64;
  const u16* Kbase = QKVh + (size_t)(b * 2048) * 3072 + 1024 + h * 64;
  const u16* Vbase = Vt + (size_t)(h * 64) * 4096 + b * 2048;

  // Q fragments (B-operand of swapped QK): col = s = l31, k = e = hi*8+i
  s16x8 qf[4];
#pragma unroll
  for (int ks = 0; ks < 4; ++ks)
    qf[ks] = *(const s16x8*)(Qbase + (size_t)(w * 32 + l31) * 3072 + ks * 16 + hi * 8);

  f32x16 accO0, accO1;
#pragma unroll
  for (int i = 0; i < 16; ++i) { accO0[i] = 0.f; accO1[i] = 0.f; }
  float lrun = 0.f;

  const float CSC = 0.18033688011112042f;  // (1/sqrt(64)) * log2(e)
  const float M2 = 12.0f;                  // fixed max shift (log2 domain)

  // staging: 256 threads stage 64x64 K and V tiles (2x16B per thread each)
  const int sr = tid >> 3, ch = tid & 7;
  const int sswz = (sr & 7) << 4;
  const u16* Kg = Kbase + (size_t)sr * 3072 + ch * 8;
  const u16* Vg = Vbase + (size_t)sr * 4096 + ch * 8;

  // prologue: tile 0 -> regs (round-8-verified pattern)
  s16x8 kreg0 = *(const s16x8*)Kg;
  s16x8 kreg1 = *(const s16x8*)(Kg + (size_t)32 * 3072);
  s16x8 vreg0 = *(const s16x8*)Vg;
  s16x8 vreg1 = *(const s16x8*)(Vg + (size_t)32 * 4096);
  Kg += (size_t)64 * 3072;
  Vg += 64;

  char* const kb = (char*)&KVsh[0][0];
  char* const vb = (char*)&KVsh[1][0];
  char* const pbase = (char*)&Psh[w][0];

  for (int kt = 0; kt < 32; ++kt) {
    if (kt) __syncthreads();   // all reads of tile kt-1 done before overwrite
    *(s16x8*)(kb + sr * 128 + ((ch * 16) ^ sswz)) = kreg0;
    *(s16x8*)(kb + (sr + 32) * 128 + ((ch * 16) ^ sswz)) = kreg1;
    *(s16x8*)(vb + sr * 128 + ((ch * 16) ^ sswz)) = vreg0;
    *(s16x8*)(vb + (sr + 32) * 128 + ((ch * 16) ^ sswz)) = vreg1;
    __syncthreads();           // all writes of tile kt done before reads

    // issue next tile's register loads; latency hides under compute kt
    if (kt < 31) {
      kreg0 = *(const s16x8*)Kg;
      kreg1 = *(const s16x8*)(Kg + (size_t)32 * 3072);
      vreg0 = *(const s16x8*)Vg;
      vreg1 = *(const s16x8*)(Vg + (size_t)32 * 4096);
      Kg += (size_t)64 * 3072;
      Vg += 64;
    }

    // ---- QK swapped: sc[tf] = K-rows x Q -> D[t][s], s = l31 ----
    f32x16 sc0, sc1;
#pragma unroll
    for (int i = 0; i < 16; ++i) { sc0[i] = 0.f; sc1[i] = 0.f; }
#pragma unroll
    for (int ks = 0; ks < 4; ++ks) {
      s16x8 ka0 = *(const s16x8*)(kb + l31 * 128 + ((ks * 32 + hi * 16) ^ swz));
      s16x8 ka1 = *(const s16x8*)(kb + (32 + l31) * 128 + ((ks * 32 + hi * 16) ^ swz));
      sc0 = mfma32(ka0, qf[ks], sc0);
      sc1 = mfma32(ka1, qf[ks], sc1);
    }

    // ---- fixed-max softmax numerator + in-lane row-sum ----
    float ls = 0.f;
#pragma unroll
    for (int i = 0; i < 16; ++i) {
      sc0[i] = fast_exp2(fmaf(sc0[i], CSC, -M2));
      ls += sc0[i];
    }
#pragma unroll
    for (int i = 0; i < 16; ++i) {
      sc1[i] = fast_exp2(fmaf(sc1[i], CSC, -M2));
      ls += sc1[i];
    }
    lrun += ls + __shfl_xor(ls, 32);   // partner hi-half holds the other 32 t

    // ---- P -> LDS: 8 x b64 packed writes (t-contiguous reg quads) ----
    // reg 4q+r holds t = tf*32 + 8q + 4hi + r  -> byte tb = tf*64+16q+8hi
#pragma unroll
    for (int q = 0; q < 4; ++q) {
      u32x2 d0, d1;
      d0[0] = f2bf2(sc0[4 * q + 0], sc0[4 * q + 1]);
      d0[1] = f2bf2(sc0[4 * q + 2], sc0[4 * q + 3]);
      *(u32x2*)(pbase + l31 * 128 + ((q * 16 + hi * 8) ^ swz)) = d0;
      d1[0] = f2bf2(sc1[4 * q + 0], sc1[4 * q + 1]);
      d1[1] = f2bf2(sc1[4 * q + 2], sc1[4 * q + 3]);
      *(u32x2*)(pbase + l31 * 128 + ((64 + q * 16 + hi * 8) ^ swz)) = d1;
    }
    asm volatile("s_waitcnt lgkmcnt(0)" ::: "memory");  // wave-internal wr->rd
    __builtin_amdgcn_sched_barrier(0);                  // rule #18 fence

    // ---- PV swapped: accO[ef] = V^T-rows x P -> D[e][s], s = l31 ----
#pragma unroll
    for (int ks = 0; ks < 4; ++ks) {
      s16x8 pb  = *(const s16x8*)(pbase + l31 * 128 + ((ks * 32 + hi * 16) ^ swz));
      s16x8 va0 = *(const s16x8*)(vb + l31 * 128 + ((ks * 32 + hi * 16) ^ swz));
      s16x8 va1 = *(const s16x8*)(vb + (32 + l31) * 128 + ((ks * 32 + hi * 16) ^ swz));
      accO0 = mfma32(va0, pb, accO0);
      accO1 = mfma32(va1, pb, accO1);
    }
  }

  // ---- epilogue: O^T regs -> wave-local LDS -> coalesced global ----
  __syncthreads();             // protect KVsh reuse from straggler waves (r3)
  const float inv = 1.f / lrun;
  char* osh = kb + w * 4096;   // 4 waves x 4KB spans KVsh[0]+KVsh[1]
#pragma unroll
  for (int q = 0; q < 4; ++q) {
    u32x2 d0, d1;               // e = ef*32 + 8q + 4hi + r  <-> acc[4q+r]
    d0[0] = f2bf2(accO0[4 * q + 0] * inv, accO0[4 * q + 1] * inv);
    d0[1] = f2bf2(accO0[4 * q + 2] * inv, accO0[4 * q + 3] * inv);
    *(u32x2*)(osh + l31 * 128 + ((q * 16 + hi * 8) ^ swz)) = d0;
    d1[0] = f2bf2(accO1[4 * q + 0] * inv, accO1[4 * q + 1] * inv);
    d1[1] = f2bf2(accO1[4 * q + 2] * inv, accO1[4 * q + 3] * inv);
    *(u32x2*)(osh + l31 * 128 + ((64 + q * 16 + hi * 8) ^ swz)) = d1;
  }
  asm volatile("s_waitcnt lgkmcnt(0)" ::: "memory");
  __builtin_amdgcn_sched_barrier(0);
  u16* Ob = Obuf + (rowQ + w * 32) * 1024 + h * 64;
#pragma unroll
  for (int c = 0; c < 4; ++c) {
    int idx = lane + c * 64;
    int row = idx >> 3, cc = idx & 7;
    s16x8 v = *(const s16x8*)(osh + row * 128 + ((cc * 16) ^ ((row & 7) << 4)));
    *(s16x8*)(Ob + (size_t)row * 1024 + cc * 8) = v;
  }
}

// ---------------- launch ----------------
extern "C" void kernel_launch(void* const* d_in, const int* in_sizes, int n_in,
                              void* d_out, int out_size, void* d_ws, size_t ws_size,
                              hipStream_t stream) {
  const float* Q  = (const float*)d_in[0];
  const float* K  = (const float*)d_in[1];
  const float* V  = (const float*)d_in[2];
  const float* Wq = (const float*)d_in[3];
  const float* bq = (const float*)d_in[4];
  const float* Wk = (const float*)d_in[5];
  const float* bk = (const float*)d_in[6];
  const float* Wv = (const float*)d_in[7];
  const float* bv = (const float*)d_in[8];
  const float* Wf = (const float*)d_in[9];
  const float* bf = (const float*)d_in[10];
  float* out = (float*)d_out;
  char* ws = (char*)d_ws;

  u16*   QKVbf  = (u16*)(ws + OFF_QBF);   // Q|K|V bf16 contiguous
  u16*   Qbf    = (u16*)(ws + OFF_QBF);
  u16*   Kbf    = (u16*)(ws + OFF_KBF);
  u16*   Vbf    = (u16*)(ws + OFF_VBF);
  u16*   Wcat   = (u16*)(ws + OFF_WCAT);
  u16*   WfT    = (u16*)(ws + OFF_WFT);
  float* biascat= (float*)(ws + OFF_BIAS);
  u16*   QKVh   = (u16*)(ws + OFF_QKVH);
  u16*   Vt     = (u16*)(ws + OFF_VT);
  u16*   Obuf   = (u16*)(ws + OFF_OBUF);

  dim3 blk(256);
  prep_all_k<<<13324, blk, 0, stream>>>(Q, K, V, Wq, Wk, Wv, Wf, bq, bk, bv,
                                        QKVbf, Wcat, WfT, biascat);
  proj_gemm_k<<<dim3(8, 32, 3), blk, 0, stream>>>(Qbf, Kbf, Vbf, Wcat, biascat,
                                                  QKVh, Vt);
  attn10_k<<<dim3(512), blk, 0, stream>>>(QKVh, Vt, Obuf);
  final_gemm_k<<<dim3(8, 32), blk, 0, stream>>>(Obuf, WfT, bf, out);
}